// Round 2
// baseline (140.853 us; speedup 1.0000x reference)
//
#include <hip/hip_runtime.h>

// APG_Linear: out[b] = ((inp[b] @ U) @ W_b) @ V + bias
//   B=131072, IN=128, OUT=128, RANK=32, all f32.
// Memory-bound: 671 MB total traffic, gen_weight (537 MB) dominates.
// One row per wave; W read as 4x dwordx4/lane (coalesced), register
// double-buffered; U in LDS, V+bias in registers.

constexpr int RANK  = 32;
constexpr int BLOCK = 256;            // 4 waves/block
constexpr int WPB   = BLOCK / 64;
constexpr int GRID  = 1024;
constexpr int NWAVES = GRID * WPB;    // 4096 waves -> 32 rows/wave at B=131072

__global__ __launch_bounds__(BLOCK, 2)
void apg_linear_kernel(const float* __restrict__ inp,
                       const float* __restrict__ gw,
                       const float* __restrict__ U,
                       const float* __restrict__ V,
                       const float* __restrict__ bias,
                       float* __restrict__ out,
                       int nrows)
{
    __shared__ float4 u4s[1024];        // U staged: 128x32 f32 = 16 KiB
    __shared__ float  hbuf[WPB][RANK];  // per-wave h round-trip (128 B each)

    const int tid  = threadIdx.x;
    const int lane = tid & 63;
    const int wid  = tid >> 6;
    const int g    = lane >> 3;         // 0..7

    // ---- stage U into LDS (flat float4 layout: u4s[f] = U[4f..4f+3]) ----
    #pragma unroll
    for (int j = 0; j < 4; ++j)
        u4s[j * BLOCK + tid] = reinterpret_cast<const float4*>(U)[j * BLOCK + tid];
    __syncthreads();

    // ---- V and bias in registers: lane owns output cols {2*lane, 2*lane+1} ----
    float2 v2[RANK];
    #pragma unroll
    for (int r = 0; r < RANK; ++r)
        v2[r] = reinterpret_cast<const float2*>(V + r * 128)[lane];
    const float2 b2 = reinterpret_cast<const float2*>(bias)[lane];

    float* hw = hbuf[wid];

    const int wave0 = blockIdx.x * WPB + wid;
    const int iters = (nrows + NWAVES - 1) / NWAVES;   // 32 at B=131072

    int row = wave0;
    // ---- prefetch row 0 ----
    float x0n = 0.f, x1n = 0.f;
    float4 w4n[4] = {};
    if (row < nrows) {
        x0n = inp[row * 128 + lane];
        x1n = inp[row * 128 + 64 + lane];
        const float4* wp = reinterpret_cast<const float4*>(gw) + row * 256;
        #pragma unroll
        for (int t = 0; t < 4; ++t) w4n[t] = wp[t * 64 + lane];
    }

    for (int it = 0; it < iters; ++it) {
        if (row >= nrows) break;
        const float x0 = x0n, x1 = x1n;
        float4 w4[4];
        #pragma unroll
        for (int t = 0; t < 4; ++t) w4[t] = w4n[t];

        // ---- prefetch next row (overlaps with compute below) ----
        const int nrow = row + NWAVES;
        if (it + 1 < iters && nrow < nrows) {
            x0n = inp[nrow * 128 + lane];
            x1n = inp[nrow * 128 + 64 + lane];
            const float4* wp = reinterpret_cast<const float4*>(gw) + nrow * 256;
            #pragma unroll
            for (int t = 0; t < 4; ++t) w4n[t] = wp[t * 64 + lane];
        }

        // ---- step 1: h = inp_row @ U -------------------------------------
        // lane accumulates h[4c..4c+3] (c = lane&7) over i = t*8+g, t=0..15
        float h1a[4] = {0.f, 0.f, 0.f, 0.f};
        #pragma unroll
        for (int t = 0; t < 16; ++t) {
            const float xs = (t < 8) ? x0 : x1;            // t is constant
            const float xi = __shfl(xs, (t & 7) * 8 + g, 64);
            const float4 u = u4s[t * 64 + lane];
            h1a[0] = fmaf(xi, u.x, h1a[0]);
            h1a[1] = fmaf(xi, u.y, h1a[1]);
            h1a[2] = fmaf(xi, u.z, h1a[2]);
            h1a[3] = fmaf(xi, u.w, h1a[3]);
        }
        #pragma unroll
        for (int s = 8; s <= 32; s <<= 1) {
            #pragma unroll
            for (int k = 0; k < 4; ++k)
                h1a[k] += __shfl_xor(h1a[k], s, 64);
        }
        // park h in per-wave LDS so step 2 can index it per-lane
        if (lane < 8)
            reinterpret_cast<float4*>(hw)[lane] =
                make_float4(h1a[0], h1a[1], h1a[2], h1a[3]);

        // ---- step 2: h2 = h @ W_b ----------------------------------------
        float h2a[4] = {0.f, 0.f, 0.f, 0.f};
        #pragma unroll
        for (int t = 0; t < 4; ++t) {
            const float hi = hw[t * 8 + g];                // broadcast read
            h2a[0] = fmaf(hi, w4[t].x, h2a[0]);
            h2a[1] = fmaf(hi, w4[t].y, h2a[1]);
            h2a[2] = fmaf(hi, w4[t].z, h2a[2]);
            h2a[3] = fmaf(hi, w4[t].w, h2a[3]);
        }
        #pragma unroll
        for (int s = 8; s <= 32; s <<= 1) {
            #pragma unroll
            for (int k = 0; k < 4; ++k)
                h2a[k] += __shfl_xor(h2a[k], s, 64);
        }

        // ---- step 3: out_row = h2 @ V + bias -----------------------------
        float o0 = b2.x, o1 = b2.y;
        #pragma unroll
        for (int r = 0; r < RANK; ++r) {
            const float h2r = __shfl(h2a[r & 3], r >> 2, 64); // uniform lane
            o0 = fmaf(h2r, v2[r].x, o0);
            o1 = fmaf(h2r, v2[r].y, o1);
        }
        reinterpret_cast<float2*>(out)[row * 64 + lane] = make_float2(o0, o1);

        row = nrow;
    }
}

extern "C" void kernel_launch(void* const* d_in, const int* in_sizes, int n_in,
                              void* d_out, int out_size, void* d_ws, size_t ws_size,
                              hipStream_t stream)
{
    const float* inp  = (const float*)d_in[0];
    const float* gw   = (const float*)d_in[1];
    const float* U    = (const float*)d_in[2];
    const float* V    = (const float*)d_in[3];
    const float* bias = (const float*)d_in[4];
    float* out = (float*)d_out;
    const int nrows = in_sizes[0] / 128;   // B = 131072

    apg_linear_kernel<<<GRID, BLOCK, 0, stream>>>(inp, gw, U, V, bias, out, nrows);
}